// Round 1
// baseline (29663.162 us; speedup 1.0000x reference)
//
#include <hip/hip_runtime.h>

// Problem constants
// B=64, T=512, H=1024, L=2; gates 4H=4096 per dir
// out layout (floats): out[B][T][2H] @0, c_out @67108864, out_last @134217728, c_out_last @134348800

typedef __attribute__((ext_vector_type(8))) short ab8;
typedef __attribute__((ext_vector_type(4))) float f32x4;

static __device__ __forceinline__ short f2bf(float f) {
  union { float f; unsigned u; } v; v.f = f;
  unsigned r = v.u + 0x7fff + ((v.u >> 16) & 1);   // RNE
  return (short)(r >> 16);
}

// ---------------------------------------------------------------------------
// Prep: fp32 weights -> bf16, with layer-0 backward Wih column-reversed
// layout: 8 matrices of 4096x1024: [l][q], q: 0=Wih_f 1=Whh_f 2=Wih_b(rev if l==0) 3=Whh_b
__global__ void prep_weights(const float* __restrict__ Wih_f, const float* __restrict__ Whh_f,
                             const float* __restrict__ Wih_b, const float* __restrict__ Whh_b,
                             short* __restrict__ Wo) {
  long i = (long)blockIdx.x * blockDim.x + threadIdx.x;
  if (i >= (8L << 22)) return;
  int s = (int)(i >> 22);
  int rem = (int)(i & 4194303);
  int row = rem >> 10;
  int k = rem & 1023;
  int l = s >> 2, q = s & 3;
  const float* p;
  int kk = k;
  if (q == 0) p = Wih_f;
  else if (q == 1) p = Whh_f;
  else if (q == 2) { p = Wih_b; if (l == 0) kk = 1023 - k; }
  else p = Whh_b;
  float v = p[((long)(l * 4096 + row) << 10) + kk];
  Wo[i] = f2bf(v);
}

__global__ void prep_x(const float* __restrict__ x, short* __restrict__ xb) {
  long i = (long)blockIdx.x * blockDim.x + threadIdx.x;
  if (i >= 33554432L) return;  // 64*512*1024
  xb[i] = f2bf(x[i]);
}

// combined biases (bih+bhh) per [l][dir], zero-init h/c state slots
__global__ void prep_misc(const float* __restrict__ bih_f, const float* __restrict__ bhh_f,
                          const float* __restrict__ bih_b, const float* __restrict__ bhh_b,
                          float* __restrict__ bias, short* __restrict__ hb_state,
                          float* __restrict__ c_state, short* __restrict__ hf_tmp) {
  int i = blockIdx.x * blockDim.x + threadIdx.x;
  if (i < 16384) {
    int slot = i >> 12;       // l*2+dir
    int j = i & 4095;
    int l = slot >> 1, d = slot & 1;
    float v = d ? (bih_b[(l << 12) + j] + bhh_b[(l << 12) + j])
                : (bih_f[(l << 12) + j] + bhh_f[(l << 12) + j]);
    bias[i] = v;
  }
  if (i < 262144) hb_state[i] = 0;   // 2 layers x 2 slots x 64x1024 bf16
  if (i < 262144) c_state[i] = 0.f;  // 2 layers x 2 slots x 64x1024 f32
  if (i < 65536) hf_tmp[i] = 0;
}

// ---------------------------------------------------------------------------
// One LSTM step for one layer, both directions.
// Grid: 256 blocks = dir(2) x unitTile(64, 16 units each) x batchHalf(2, 32 rows).
// Block: 256 threads = 4 waves, wave g computes gate g: tile M=32 x N=16, K=2048.
// A (activations) and B (weight rows) both load contiguous 16B along k.
__global__ __launch_bounds__(256) void lstm_step(
    const short* __restrict__ Axf, const short* __restrict__ Axb, long sAx,
    const short* __restrict__ Hprev,
    const short* __restrict__ Wl,          // this layer: [Wih_f, Whh_f, Wih_b, Whh_b] each 2^22
    const float* __restrict__ biasF, const float* __restrict__ biasB,
    const float* __restrict__ Cprev, float* __restrict__ CnewB,
    short* __restrict__ HnewF, short* __restrict__ HnewB,
    float* __restrict__ outH, float* __restrict__ outC, int lay1) {
  int bid = blockIdx.x;
  int dir = bid >> 7;
  int r2 = bid & 127;
  int u0 = (r2 >> 1) << 4;
  int b0 = (r2 & 1) << 5;
  int tid = threadIdx.x;
  int wid = tid >> 6;          // gate index: 0=i 1=f 2=g 3=o
  int lane = tid & 63;
  int lr = lane & 15;          // m (A) / n (B,C)
  int lk = (lane >> 4) << 3;   // k offset within 32-chunk

  const short* Ax = dir ? Axb : Axf;
  const short* Wx = Wl + ((long)(dir ? 2 : 0) << 22);
  const short* Wh = Wl + ((long)(dir ? 3 : 1) << 22);
  const float* bias = dir ? biasB : biasF;

  f32x4 acc0 = {0.f, 0.f, 0.f, 0.f};
  f32x4 acc1 = {0.f, 0.f, 0.f, 0.f};

  // phase X: k in [0,1024) from layer input
  {
    const short* a0p = Ax + (long)(b0 + lr) * sAx + lk;
    const short* a1p = Ax + (long)(b0 + 16 + lr) * sAx + lk;
    const short* bp  = Wx + ((long)((wid << 10) + u0 + lr) << 10) + lk;
#pragma unroll 4
    for (int k0 = 0; k0 < 1024; k0 += 32) {
      ab8 a0 = *(const ab8*)(a0p + k0);
      ab8 a1 = *(const ab8*)(a1p + k0);
      ab8 bb = *(const ab8*)(bp + k0);
      acc0 = __builtin_amdgcn_mfma_f32_16x16x32_bf16(a0, bb, acc0, 0, 0, 0);
      acc1 = __builtin_amdgcn_mfma_f32_16x16x32_bf16(a1, bb, acc1, 0, 0, 0);
    }
  }
  // phase H: k in [0,1024) from shared h_prev (backward carry)
  {
    const short* a0p = Hprev + ((b0 + lr) << 10) + lk;
    const short* a1p = Hprev + ((b0 + 16 + lr) << 10) + lk;
    const short* bp  = Wh + ((long)((wid << 10) + u0 + lr) << 10) + lk;
#pragma unroll 4
    for (int k0 = 0; k0 < 1024; k0 += 32) {
      ab8 a0 = *(const ab8*)(a0p + k0);
      ab8 a1 = *(const ab8*)(a1p + k0);
      ab8 bb = *(const ab8*)(bp + k0);
      acc0 = __builtin_amdgcn_mfma_f32_16x16x32_bf16(a0, bb, acc0, 0, 0, 0);
      acc1 = __builtin_amdgcn_mfma_f32_16x16x32_bf16(a1, bb, acc1, 0, 0, 0);
    }
  }

  // stage gates in LDS: gb[gate][m 0..31][n 0..15]
  __shared__ float gb[4][32][17];
  float bv = bias[(wid << 10) + u0 + lr];
  int mrow = (lane >> 4) << 2;  // C/D: row = 4*(lane>>4)+reg, col = lane&15
#pragma unroll
  for (int rr = 0; rr < 4; rr++) {
    gb[wid][mrow + rr][lr] = acc0[rr] + bv;
    gb[wid][16 + mrow + rr][lr] = acc1[rr] + bv;
  }
  __syncthreads();

  // cell update: 32x16 (b,u) pairs
  for (int idx = tid; idx < 512; idx += 256) {
    int m = idx >> 4, n = idx & 15;
    int b = b0 + m, u = u0 + n;
    float gi = gb[0][m][n], gf = gb[1][m][n], gg = gb[2][m][n], go = gb[3][m][n];
    float cp = Cprev[(b << 10) + u];
    float si = 1.f / (1.f + __expf(-gi));
    float sf = 1.f / (1.f + __expf(-gf));
    float so = 1.f / (1.f + __expf(-go));
    float ag = fabsf(gg);
    float tg = 1.f - 2.f / (__expf(2.f * ag) + 1.f);
    tg = gg < 0.f ? -tg : tg;
    float cn = sf * cp + si * tg;
    float ac = fabsf(cn);
    float tc = 1.f - 2.f / (__expf(2.f * ac) + 1.f);
    tc = cn < 0.f ? -tc : tc;
    float hn = so * tc;
    if (dir == 0) {
      HnewF[(b << 10) + u] = f2bf(hn);
      if (lay1) {
        outH[(long)b * 1048576 + u] = hn;
        outC[(long)b * 1048576 + u] = cn;
      }
    } else {
      HnewB[(b << 10) + u] = f2bf(hn);
      CnewB[(b << 10) + u] = cn;
      if (lay1) {
        outH[(long)b * 1048576 + 1024 + u] = hn;
        outC[(long)b * 1048576 + 1024 + u] = cn;
      }
    }
  }
}

__global__ void copy_last(float* __restrict__ dout) {
  int i = blockIdx.x * blockDim.x + threadIdx.x;
  if (i >= 131072) return;  // 64 * 2048
  int b = i >> 11, u = i & 2047;
  long src = (long)b * 1048576 + 1046528 + u;  // t = 511
  dout[134217728L + i] = dout[src];
  dout[134217728L + 131072 + i] = dout[67108864L + src];
}

// ---------------------------------------------------------------------------
extern "C" void kernel_launch(void* const* d_in, const int* in_sizes, int n_in,
                              void* d_out, int out_size, void* d_ws, size_t ws_size,
                              hipStream_t stream) {
  const float* x     = (const float*)d_in[0];
  const float* Wih_f = (const float*)d_in[1];
  const float* Whh_f = (const float*)d_in[2];
  const float* bih_f = (const float*)d_in[3];
  const float* bhh_f = (const float*)d_in[4];
  const float* Wih_b = (const float*)d_in[5];
  const float* Whh_b = (const float*)d_in[6];
  const float* bih_b = (const float*)d_in[7];
  const float* bhh_b = (const float*)d_in[8];
  float* dout = (float*)d_out;

  char* ws = (char*)d_ws;
  short* xb   = (short*)ws; ws += 67108864;   // x in bf16, (B,T,H)
  short* Wb   = (short*)ws; ws += 67108864;   // 8 matrices bf16
  float* bias = (float*)ws; ws += 65536;      // 4 x 4096 combined
  short* hbs  = (short*)ws; ws += 524288;     // h state: [l][slot][64*1024] bf16
  float* cst  = (float*)ws; ws += 1048576;    // c state: [l][slot][64*1024] f32
  short* hft  = (short*)ws; ws += 131072;     // h_f0(t) scratch bf16
  short* hfd  = (short*)ws; ws += 131072;     // dummy sink for layer-1 fwd h bf16

  prep_weights<<<131072, 256, 0, stream>>>(Wih_f, Whh_f, Wih_b, Whh_b, Wb);
  prep_x<<<131072, 256, 0, stream>>>(x, xb);
  prep_misc<<<1024, 256, 0, stream>>>(bih_f, bhh_f, bih_b, bhh_b, bias, hbs, cst, hft);

  for (int t = 0; t < 512; t++) {
    int r = t & 1, w = 1 - r;
    // layer 0: input = x_t for both dirs (reversal folded into Wih_b0)
    lstm_step<<<256, 256, 0, stream>>>(
        xb + (long)t * 1024, xb + (long)t * 1024, 524288L,
        hbs + 0 * 131072 + r * 65536,
        Wb,
        bias, bias + 4096,
        cst + 0 * 262144 / 1 * 0 + r * 65536, cst + w * 65536,  // layer 0 c slots
        hft, hbs + 0 * 131072 + w * 65536,
        nullptr, nullptr, 0);
    // layer 1: inputs = h_f0(t), h_b0(t); writes out/c_out
    lstm_step<<<256, 256, 0, stream>>>(
        hft, hbs + 0 * 131072 + w * 65536, 1024L,
        hbs + 1 * 131072 + r * 65536,
        Wb + (4L << 22),
        bias + 8192, bias + 12288,
        cst + 131072 + r * 65536, cst + 131072 + w * 65536,
        hfd, hbs + 1 * 131072 + w * 65536,
        dout + (long)t * 2048, dout + 67108864L + (long)t * 2048, 1);
  }
  copy_last<<<512, 256, 0, stream>>>(dout);
}